// Round 5
// baseline (205.184 us; speedup 1.0000x reference)
//
#include <hip/hip_runtime.h>

// ITA Self-Attention QAT — round 5 (256^2 2-phase QKV GEMM + tiled transpose)
// B=8, N=1024, E=768, P=768, H=12, D=64
//
// vs round 4 (passed, 202.6us): QKV gemm was 96-104us @ MfmaUtil 12% —
// latency-bound: 16 MFMA (~80cy) per barrier drain (~500cy). Fix: 256x256
// tile, BK=64, 8 waves, 128KB dbuf LDS -> 64 MFMA/wave per barrier, plus
// XOR-swizzled LDS via pre-swizzled global source (conflict-free ds_read).
// prep_weights: strided column reads -> LDS-tiled 64x64 transpose.
// attn + final 128^2 gemm unchanged.

typedef unsigned short u16;
typedef __attribute__((ext_vector_type(8))) short short8;
typedef __attribute__((ext_vector_type(8))) _Float16 half8;
typedef __attribute__((ext_vector_type(4))) float f32x4;

#define LOG2E_F 1.4426950408889634f

static __device__ __forceinline__ half8 s2h(short8 s) {
  union { short8 s; half8 h; } u; u.s = s; return u.h;
}
static __device__ __forceinline__ f32x4 mfma16(short8 a, short8 b, f32x4 c) {
  return __builtin_amdgcn_mfma_f32_16x16x32_f16(s2h(a), s2h(b), c, 0, 0, 0);
}
static __device__ __forceinline__ u16 f2h(float f) {
  union { _Float16 h; u16 u; } v; v.h = (_Float16)f; return v.u;
}
static __device__ __forceinline__ void gload16(const void* g, void* l) {
  __builtin_amdgcn_global_load_lds(
      (const __attribute__((address_space(1))) void*)g,
      (__attribute__((address_space(3))) void*)l, 16, 0, 0);
}

// ---------------- amax reduction ----------------
__global__ __launch_bounds__(256) void amax_part_kernel(
    const float4* __restrict__ x, float* __restrict__ part, int n4) {
  float m = 0.f;
  int i = blockIdx.x * 256 + threadIdx.x;
  const int stride = gridDim.x * 256;
  for (; i < n4; i += stride) {
    float4 v = x[i];
    m = fmaxf(m, fmaxf(fmaxf(fabsf(v.x), fabsf(v.y)),
                       fmaxf(fabsf(v.z), fabsf(v.w))));
  }
  #pragma unroll
  for (int o = 1; o < 64; o <<= 1) m = fmaxf(m, __shfl_xor(m, o));
  __shared__ float sw[4];
  if ((threadIdx.x & 63) == 0) sw[threadIdx.x >> 6] = m;
  __syncthreads();
  if (threadIdx.x == 0)
    part[blockIdx.x] = fmaxf(fmaxf(sw[0], sw[1]), fmaxf(sw[2], sw[3]));
}

__global__ __launch_bounds__(256) void amax_fin_kernel(
    const float* __restrict__ part, double* __restrict__ dsc,
    float* __restrict__ dscf) {
  const int t = threadIdx.x;
  float m = fmaxf(fmaxf(part[t], part[t + 256]),
                  fmaxf(part[t + 512], part[t + 768]));
  #pragma unroll
  for (int o = 1; o < 64; o <<= 1) m = fmaxf(m, __shfl_xor(m, o));
  __shared__ float sw[4];
  if ((t & 63) == 0) sw[t >> 6] = m;
  __syncthreads();
  if (t == 0) {
    double sd = (double)(fmaxf(fmaxf(sw[0], sw[1]), fmaxf(sw[2], sw[3]))) / 127.0;
    if (sd < 1e-8) sd = 1e-8;
    dsc[0] = sd;
    dsc[1] = 1.0 / sd;
    dscf[0] = (float)sd;
  }
}

// ---------------- quantize: xq = clip(rint(x/s),-128,127), exact in f16 -----
__global__ __launch_bounds__(256) void quant_kernel(
    const float4* __restrict__ x, u16* __restrict__ xq,
    const double* __restrict__ dsc, int n4) {
  const double rinv = dsc[1];
  int i = blockIdx.x * 256 + threadIdx.x;
  const int stride = gridDim.x * 256;
  for (; i < n4; i += stride) {
    float4 v = x[i];
    ushort4 u;
    u.x = f2h((float)fmin(fmax(rint((double)v.x * rinv), -128.0), 127.0));
    u.y = f2h((float)fmin(fmax(rint((double)v.y * rinv), -128.0), 127.0));
    u.z = f2h((float)fmin(fmax(rint((double)v.z * rinv), -128.0), 127.0));
    u.w = f2h((float)fmin(fmax(rint((double)v.w * rinv), -128.0), 127.0));
    *(ushort4*)&xq[(size_t)i * 4] = u;
  }
}

// ------- weight prep: LDS-tiled transpose fp32->f16 (coalesced both sides) --
// grid.x = 144 tiles (12x12 of 64x64), grid.y = 4 (mat: Wq,Wk,Wv,Wo)
// Wcat rows: [0,768)=Wq^T, [768,1536)=Wk^T, [1536,2304)=Wv^T.
__global__ __launch_bounds__(256) void prep_weights_kernel(
    const float* __restrict__ Wq, const float* __restrict__ Wk,
    const float* __restrict__ Wv, const float* __restrict__ Wo,
    const float* __restrict__ bq, const float* __restrict__ bk,
    const float* __restrict__ bv,
    u16* __restrict__ Wcat, u16* __restrict__ Wot, float* __restrict__ bcat) {
  __shared__ float t[64][65];
  const int m = blockIdx.y;
  const float* src = (m == 0) ? Wq : (m == 1) ? Wk : (m == 2) ? Wv : Wo;
  u16* dst = (m == 3) ? Wot : (Wcat + (size_t)m * 768 * 768);
  const int tile = blockIdx.x;
  const int r0 = (tile / 12) * 64, c0 = (tile - (tile / 12) * 12) * 64;
  const int i = threadIdx.x >> 6, j = threadIdx.x & 63;
  #pragma unroll
  for (int it = 0; it < 16; ++it) {
    const int row = it * 4 + i;
    t[row][j] = src[(size_t)(r0 + row) * 768 + c0 + j];
  }
  __syncthreads();
  #pragma unroll
  for (int it = 0; it < 16; ++it) {
    const int row = it * 4 + i;  // output row within transposed tile
    dst[(size_t)(c0 + row) * 768 + r0 + j] = f2h(t[j][row]);
  }
  if (blockIdx.x == 0 && m == 0) {
    for (int k = threadIdx.x; k < 768; k += 256) {
      bcat[k] = bq[k];
      bcat[k + 768] = bk[k];
      bcat[k + 1536] = bv[k];
    }
  }
}

// ---------------- QKV GEMM: 256x256 tile, BK=64, 8 waves, 2-phase dbuf ------
// C[m,c] = (sum_k A[m,k]*Bt[c,k]) * scale + bias[c], c in [0,2304)
// seg 0 -> Q [B,H,N,D], seg 1 -> K [B,H,N,D], seg 2 -> Vt [B,H,D,N]
// LDS XOR-swizzle via pre-swizzled global source (m173): LDS[row][cl] holds
// global chunk cl^(row&7); reads XOR the chunk index with row&7.
__global__ __launch_bounds__(512, 2) void gemm_qkv(
    const u16* __restrict__ A, const u16* __restrict__ Bt,
    const float* __restrict__ bias, const float* __restrict__ scale_p,
    u16* __restrict__ Oq, u16* __restrict__ Ok, u16* __restrict__ Ovt) {
  __shared__ u16 As[2][256 * 64];   // 64 KB
  __shared__ u16 Bs[2][256 * 64];   // 64 KB
  const int K = 768, NK = 12;
  const int tid = threadIdx.x;
  const int w = tid >> 6, l = tid & 63;
  const int l15 = l & 15, lk = l >> 4;
  const int wr = w >> 2, wc = w & 3;          // wave grid 2M x 4N
  const int xr = l15 & 7;                     // read-side XOR key
  const int tn = blockIdx.x, tm = blockIdx.y;
  f32x4 acc[8][4] = {};
  const int rA = tid >> 3;                    // staging row 0..63 (+64*i)
  const int schunk = ((tid & 7) ^ (rA & 7)) * 8;  // pre-swizzled source chunk
  const u16* gA = A + (size_t)(tm * 256 + rA) * K + schunk;
  const u16* gB = Bt + (size_t)(tn * 256 + rA) * K + schunk;

  #define STAGE(buf, kt)                                              \
    {                                                                 \
      const int k0 = (kt) * 64;                                       \
      char* lA = (char*)As[buf] + w * 1024;                           \
      char* lB = (char*)Bs[buf] + w * 1024;                           \
      _Pragma("unroll")                                               \
      for (int i = 0; i < 4; ++i) {                                   \
        gload16(gA + k0 + (size_t)(i * 64) * K, lA + i * 8192);       \
        gload16(gB + k0 + (size_t)(i * 64) * K, lB + i * 8192);       \
      }                                                               \
    }

  STAGE(0, 0)
  __syncthreads();
  for (int kt = 0; kt < NK; ++kt) {
    const int buf = kt & 1;
    if (kt + 1 < NK) STAGE(buf ^ 1, kt + 1)
    #pragma unroll
    for (int kh = 0; kh < 2; ++kh) {
      short8 af[8], bf[4];
      #pragma unroll
      for (int mi = 0; mi < 8; ++mi) {
        const int row = wr * 128 + mi * 16 + l15;
        af[mi] = *(const short8*)&As[buf][row * 64 + (((kh * 4 + lk) ^ xr) * 8)];
      }
      #pragma unroll
      for (int ni = 0; ni < 4; ++ni) {
        const int row = wc * 64 + ni * 16 + l15;
        bf[ni] = *(const short8*)&Bs[buf][row * 64 + (((kh * 4 + lk) ^ xr) * 8)];
      }
      #pragma unroll
      for (int mi = 0; mi < 8; ++mi)
        #pragma unroll
        for (int ni = 0; ni < 4; ++ni)
          acc[mi][ni] = mfma16(af[mi], bf[ni], acc[mi][ni]);
    }
    __syncthreads();   // drains vmcnt (stage) + lgkm; one barrier per K-tile
  }
  #undef STAGE

  const float s = *scale_p;
  const int seg = tn / 3;   // 256-col blocks: 3 per 768-col segment
  #pragma unroll
  for (int mi = 0; mi < 8; ++mi) {
    #pragma unroll
    for (int ni = 0; ni < 4; ++ni) {
      #pragma unroll
      for (int j = 0; j < 4; ++j) {
        const int gm = tm * 256 + wr * 128 + mi * 16 + lk * 4 + j;
        const int c = tn * 256 + wc * 64 + ni * 16 + l15;
        const int gc = c - seg * 768;
        const float v = acc[mi][ni][j] * s + bias[c];
        const int b = gm >> 10, n = gm & 1023, h = gc >> 6, d = gc & 63;
        if (seg == 0)
          Oq[(((size_t)b * 12 + h) * 1024 + n) * 64 + d] = f2h(v);
        else if (seg == 1)
          Ok[(((size_t)b * 12 + h) * 1024 + n) * 64 + d] = f2h(v);
        else
          Ovt[(((size_t)b * 12 + h) * 64 + d) * 1024 + n] = f2h(v);
      }
    }
  }
}

// ---------------- final GEMM (128x128, 2-phase dbuf), fp32 out --------------
__global__ __launch_bounds__(256) void gemm_out(
    const u16* __restrict__ A, const u16* __restrict__ Bt,
    const float* __restrict__ bias, float* __restrict__ Of) {
  __shared__ u16 As[2][128 * 32];
  __shared__ u16 Bs[2][128 * 32];
  const int K = 768, nk = 24;
  const int tid = threadIdx.x;
  const int w = tid >> 6, l = tid & 63;
  const int l15 = l & 15, lk = l >> 4;
  const int wr = w >> 1, wc = w & 1;
  const int tn = blockIdx.x, tm = blockIdx.y;
  f32x4 acc[4][4] = {};
  const int rA = tid >> 2;
  const int c8 = (tid & 3) * 8;
  const u16* gA = A + (size_t)(tm * 128 + rA) * K + c8;
  const u16* gB = Bt + (size_t)(tn * 128 + rA) * K + c8;
  {
    char* lA = (char*)As[0] + w * 1024;
    char* lB = (char*)Bs[0] + w * 1024;
    gload16(gA, lA);
    gload16(gA + (size_t)64 * K, lA + 4096);
    gload16(gB, lB);
    gload16(gB + (size_t)64 * K, lB + 4096);
  }
  __syncthreads();
  for (int kt = 0; kt < nk; ++kt) {
    const int buf = kt & 1;
    if (kt + 1 < nk) {
      const int k0 = (kt + 1) * 32;
      char* lA = (char*)As[buf ^ 1] + w * 1024;
      char* lB = (char*)Bs[buf ^ 1] + w * 1024;
      gload16(gA + k0, lA);
      gload16(gA + k0 + (size_t)64 * K, lA + 4096);
      gload16(gB + k0, lB);
      gload16(gB + k0 + (size_t)64 * K, lB + 4096);
    }
    short8 af[4], bf[4];
    #pragma unroll
    for (int mi = 0; mi < 4; ++mi)
      af[mi] = *(const short8*)&As[buf][(wr * 64 + mi * 16 + l15) * 32 + lk * 8];
    #pragma unroll
    for (int ni = 0; ni < 4; ++ni)
      bf[ni] = *(const short8*)&Bs[buf][(wc * 64 + ni * 16 + l15) * 32 + lk * 8];
    #pragma unroll
    for (int mi = 0; mi < 4; ++mi)
      #pragma unroll
      for (int ni = 0; ni < 4; ++ni)
        acc[mi][ni] = mfma16(af[mi], bf[ni], acc[mi][ni]);
    __syncthreads();
  }
  #pragma unroll
  for (int mi = 0; mi < 4; ++mi)
    #pragma unroll
    for (int ni = 0; ni < 4; ++ni)
      #pragma unroll
      for (int j = 0; j < 4; ++j) {
        const int gm = tm * 128 + wr * 64 + mi * 16 + lk * 4 + j;
        const int c = tn * 128 + wc * 64 + ni * 16 + l15;
        Of[(size_t)gm * 768 + c] = acc[mi][ni][j] + bias[c];
      }
}

// ---------------- fused attention (flash, 2-pass exact-max) -----------------
__global__ __launch_bounds__(512, 4) void attn_kernel(
    const u16* __restrict__ Q, const u16* __restrict__ K,
    const u16* __restrict__ Vt, u16* __restrict__ ctx) {
  __shared__ u16 Ks[2][64 * 64];   // 16 KB
  __shared__ u16 Vs[2][64 * 64];   // 16 KB
  __shared__ u16 Pw[8][16 * 40];   // 10 KB, wave-private P transpose buffers
  const int bh = blockIdx.x, qt = blockIdx.y;
  const int b = bh / 12, h = bh - b * 12;
  const int tid = threadIdx.x;
  const int w = tid >> 6, l = tid & 63;
  const int l15 = l & 15, lk = l >> 4;
  const int xr = l15 & 7;

  const size_t qoff = ((size_t)bh * 1024 + qt * 128 + w * 16 + l15) * 64 + lk * 8;
  const short8 qa0 = *(const short8*)(Q + qoff);
  const short8 qa1 = *(const short8*)(Q + qoff + 32);

  const int srow = w * 8 + (l >> 3);
  const int schunk = ((l & 7) ^ ((l >> 3) & 7)) * 8;
  const u16* Kg = K + ((size_t)bh * 1024 + srow) * 64 + schunk;
  const u16* Vg = Vt + ((size_t)bh * 64 + srow) * 1024 + schunk;
  u16* const ksd[2] = {&Ks[0][w * 512], &Ks[1][w * 512]};
  u16* const vsd[2] = {&Vs[0][w * 512], &Vs[1][w * 512]};

  // ---- pass A: exact row max ----
  f32x4 mx = {-3e38f, -3e38f, -3e38f, -3e38f};
  gload16(Kg, ksd[0]);
  __syncthreads();
  for (int kt = 0; kt < 16; ++kt) {
    const int buf = kt & 1;
    if (kt < 15) gload16(Kg + (size_t)(kt + 1) * 4096, ksd[buf ^ 1]);
    const u16* kb = Ks[buf];
    #pragma unroll
    for (int ks = 0; ks < 4; ++ks) {
      short8 k0 = *(const short8*)&kb[(ks * 16 + l15) * 64 + ((lk ^ xr) * 8)];
      short8 k1 = *(const short8*)&kb[(ks * 16 + l15) * 64 + (((lk + 4) ^ xr) * 8)];
      f32x4 sv = {0.f, 0.f, 0.f, 0.f};
      sv = mfma16(qa0, k0, sv);
      sv = mfma16(qa1, k1, sv);
      #pragma unroll
      for (int j = 0; j < 4; ++j) mx[j] = fmaxf(mx[j], sv[j]);
    }
    __syncthreads();
  }
  #pragma unroll
  for (int o = 1; o < 16; o <<= 1) {
    #pragma unroll
    for (int j = 0; j < 4; ++j) mx[j] = fmaxf(mx[j], __shfl_xor(mx[j], o));
  }
  f32x4 mz;
  #pragma unroll
  for (int j = 0; j < 4; ++j) mz[j] = mx[j] * LOG2E_F;

  // ---- pass B: recompute S, ITA softmax, PV ----
  f32x4 sum = {0.f, 0.f, 0.f, 0.f};
  f32x4 pv[4] = {};
  u16* const pw = Pw[w];
  gload16(Kg, ksd[0]);
  gload16(Vg, vsd[0]);
  __syncthreads();
  for (int kt = 0; kt < 16; ++kt) {
    const int buf = kt & 1;
    if (kt < 15) {
      gload16(Kg + (size_t)(kt + 1) * 4096, ksd[buf ^ 1]);
      gload16(Vg + (size_t)(kt + 1) * 64, vsd[buf ^ 1]);
    }
    const u16* kb = Ks[buf];
    const u16* vb = Vs[buf];
    #pragma unroll
    for (int ko = 0; ko < 2; ++ko) {
      #pragma unroll
      for (int ks2 = 0; ks2 < 2; ++ks2) {
        const int ks = ko * 2 + ks2;
        short8 k0 = *(const short8*)&kb[(ks * 16 + l15) * 64 + ((lk ^ xr) * 8)];
        short8 k1 = *(const short8*)&kb[(ks * 16 + l15) * 64 + (((lk + 4) ^ xr) * 8)];
        f32x4 sv = {0.f, 0.f, 0.f, 0.f};
        sv = mfma16(qa0, k0, sv);
        sv = mfma16(qa1, k1, sv);
        #pragma unroll
        for (int j = 0; j < 4; ++j) {
          float z = sv[j] * LOG2E_F;
          float zz = z - mz[j];
          float zi = floorf(zz);
          float p = ldexpf(1.0f + (zz - zi), (int)zi);
          sum[j] += p;
          pw[(lk * 4 + j) * 40 + ks2 * 16 + l15] = f2h(p);
        }
      }
      asm volatile("s_waitcnt lgkmcnt(0)" ::: "memory");
      short8 pa = *(const short8*)&pw[l15 * 40 + lk * 8];
      #pragma unroll
      for (int dt = 0; dt < 4; ++dt) {
        short8 vv = *(const short8*)&vb[(dt * 16 + l15) * 64 +
                                        (((lk + 4 * ko) ^ xr) * 8)];
        pv[dt] = mfma16(pa, vv, pv[dt]);
      }
    }
    __syncthreads();
  }
  #pragma unroll
  for (int o = 1; o < 16; o <<= 1) {
    #pragma unroll
    for (int j = 0; j < 4; ++j) sum[j] += __shfl_xor(sum[j], o);
  }
  const int nrow = qt * 128 + w * 16 + lk * 4;
  #pragma unroll
  for (int dt = 0; dt < 4; ++dt) {
    #pragma unroll
    for (int j = 0; j < 4; ++j) {
      float v = pv[dt][j] / sum[j];
      ctx[((size_t)b * 1024 + nrow + j) * 768 + h * 64 + dt * 16 + l15] = f2h(v);
    }
  }
}

// ---------------- host ----------------
extern "C" void kernel_launch(void* const* d_in, const int* in_sizes, int n_in,
                              void* d_out, int out_size, void* d_ws, size_t ws_size,
                              hipStream_t stream) {
  const float* x  = (const float*)d_in[0];
  const float* Wq = (const float*)d_in[1];
  const float* bq = (const float*)d_in[2];
  const float* Wk = (const float*)d_in[3];
  const float* bk = (const float*)d_in[4];
  const float* Wv = (const float*)d_in[5];
  const float* bv = (const float*)d_in[6];
  const float* Wo = (const float*)d_in[7];
  const float* bo = (const float*)d_in[8];
  float* out = (float*)d_out;

  char* ws = (char*)d_ws;
  float* part  = (float*)ws;               // 1024 f32
  double* dsc  = (double*)(ws + 4096);     // {s, 1/s} f64
  float* dscf  = (float*)(ws + 4112);      // s f32
  float* bcat  = (float*)(ws + 8192);      // 2304 f32
  size_t off = 8192 + 16384;
  const size_t WB = (size_t)768 * 768;
  const size_t XB = (size_t)8192 * 768;
  u16* xq   = (u16*)(ws + off); off += XB * 2;
  u16* Wcat = (u16*)(ws + off); off += 3 * WB * 2;
  u16* Wot  = (u16*)(ws + off); off += WB * 2;
  u16* Qb   = (u16*)(ws + off); off += XB * 2;
  u16* Kb   = (u16*)(ws + off); off += XB * 2;
  u16* Vtb  = (u16*)(ws + off); off += XB * 2;
  u16* ctx  = xq;  // xq dead after gemm_qkv; attn runs after -> safe alias
  (void)ws_size; (void)in_sizes; (void)n_in; (void)out_size;

  const int n4 = (8 * 1024 * 768) / 4;
  amax_part_kernel<<<1024, 256, 0, stream>>>((const float4*)x, part, n4);
  amax_fin_kernel<<<1, 256, 0, stream>>>(part, dsc, dscf);
  quant_kernel<<<2048, 256, 0, stream>>>((const float4*)x, xq, dsc, n4);
  prep_weights_kernel<<<dim3(144, 4), 256, 0, stream>>>(
      Wq, Wk, Wv, Wo, bq, bk, bv, Wcat, Wot, bcat);
  gemm_qkv<<<dim3(9, 32), 512, 0, stream>>>(xq, Wcat, bcat, dscf, Qb, Kb, Vtb);
  attn_kernel<<<dim3(96, 8), 512, 0, stream>>>(Qb, Kb, Vtb, ctx);
  gemm_out<<<dim3(6, 64), 256, 0, stream>>>(ctx, Wot, bo, out);
}

// Round 6
// 203.322 us; speedup vs baseline: 1.0092x; 1.0092x over previous
//
#include <hip/hip_runtime.h>

// ITA Self-Attention QAT — round 6 (XCD-swizzled 256^2 GEMMs)
// B=8, N=1024, E=768, P=768, H=12, D=64
//
// vs round 5 (205us, gemm_qkv 126us @ MfmaUtil 9%): staging traffic (221MB)
// was scattered across XCD L2s by round-robin dispatch, and 288 uniform
// blocks @ 1 block/CU ran as 2 full dispatch rounds. Fix:
//  - bijective XCD swizzle: g=bid&7 owns tm=g*4+(li&3); A-panels + B-panels
//    of one XCD fit its 4MB L2 -> staging becomes L2 traffic.
//  - final GEMM folded into the same 256^2 kernel (templated epilogue),
//    grid 96 swizzled, replacing the 128^2 version (150MB of re-reads).
// K-loop, LDS swizzle, attention, prolog: unchanged from round 5.

typedef unsigned short u16;
typedef __attribute__((ext_vector_type(8))) short short8;
typedef __attribute__((ext_vector_type(8))) _Float16 half8;
typedef __attribute__((ext_vector_type(4))) float f32x4;

#define LOG2E_F 1.4426950408889634f

static __device__ __forceinline__ half8 s2h(short8 s) {
  union { short8 s; half8 h; } u; u.s = s; return u.h;
}
static __device__ __forceinline__ f32x4 mfma16(short8 a, short8 b, f32x4 c) {
  return __builtin_amdgcn_mfma_f32_16x16x32_f16(s2h(a), s2h(b), c, 0, 0, 0);
}
static __device__ __forceinline__ u16 f2h(float f) {
  union { _Float16 h; u16 u; } v; v.h = (_Float16)f; return v.u;
}
static __device__ __forceinline__ void gload16(const void* g, void* l) {
  __builtin_amdgcn_global_load_lds(
      (const __attribute__((address_space(1))) void*)g,
      (__attribute__((address_space(3))) void*)l, 16, 0, 0);
}

// ---------------- amax reduction ----------------
__global__ __launch_bounds__(256) void amax_part_kernel(
    const float4* __restrict__ x, float* __restrict__ part, int n4) {
  float m = 0.f;
  int i = blockIdx.x * 256 + threadIdx.x;
  const int stride = gridDim.x * 256;
  for (; i < n4; i += stride) {
    float4 v = x[i];
    m = fmaxf(m, fmaxf(fmaxf(fabsf(v.x), fabsf(v.y)),
                       fmaxf(fabsf(v.z), fabsf(v.w))));
  }
  #pragma unroll
  for (int o = 1; o < 64; o <<= 1) m = fmaxf(m, __shfl_xor(m, o));
  __shared__ float sw[4];
  if ((threadIdx.x & 63) == 0) sw[threadIdx.x >> 6] = m;
  __syncthreads();
  if (threadIdx.x == 0)
    part[blockIdx.x] = fmaxf(fmaxf(sw[0], sw[1]), fmaxf(sw[2], sw[3]));
}

__global__ __launch_bounds__(256) void amax_fin_kernel(
    const float* __restrict__ part, double* __restrict__ dsc,
    float* __restrict__ dscf) {
  const int t = threadIdx.x;
  float m = fmaxf(fmaxf(part[t], part[t + 256]),
                  fmaxf(part[t + 512], part[t + 768]));
  #pragma unroll
  for (int o = 1; o < 64; o <<= 1) m = fmaxf(m, __shfl_xor(m, o));
  __shared__ float sw[4];
  if ((t & 63) == 0) sw[t >> 6] = m;
  __syncthreads();
  if (t == 0) {
    double sd = (double)(fmaxf(fmaxf(sw[0], sw[1]), fmaxf(sw[2], sw[3]))) / 127.0;
    if (sd < 1e-8) sd = 1e-8;
    dsc[0] = sd;
    dsc[1] = 1.0 / sd;
    dscf[0] = (float)sd;
  }
}

// ---------------- quantize: xq = clip(rint(x/s),-128,127), exact in f16 -----
__global__ __launch_bounds__(256) void quant_kernel(
    const float4* __restrict__ x, u16* __restrict__ xq,
    const double* __restrict__ dsc, int n4) {
  const double rinv = dsc[1];
  int i = blockIdx.x * 256 + threadIdx.x;
  const int stride = gridDim.x * 256;
  for (; i < n4; i += stride) {
    float4 v = x[i];
    ushort4 u;
    u.x = f2h((float)fmin(fmax(rint((double)v.x * rinv), -128.0), 127.0));
    u.y = f2h((float)fmin(fmax(rint((double)v.y * rinv), -128.0), 127.0));
    u.z = f2h((float)fmin(fmax(rint((double)v.z * rinv), -128.0), 127.0));
    u.w = f2h((float)fmin(fmax(rint((double)v.w * rinv), -128.0), 127.0));
    *(ushort4*)&xq[(size_t)i * 4] = u;
  }
}

// ------- weight prep: LDS-tiled transpose fp32->f16 (coalesced both sides) --
__global__ __launch_bounds__(256) void prep_weights_kernel(
    const float* __restrict__ Wq, const float* __restrict__ Wk,
    const float* __restrict__ Wv, const float* __restrict__ Wo,
    const float* __restrict__ bq, const float* __restrict__ bk,
    const float* __restrict__ bv,
    u16* __restrict__ Wcat, u16* __restrict__ Wot, float* __restrict__ bcat) {
  __shared__ float t[64][65];
  const int m = blockIdx.y;
  const float* src = (m == 0) ? Wq : (m == 1) ? Wk : (m == 2) ? Wv : Wo;
  u16* dst = (m == 3) ? Wot : (Wcat + (size_t)m * 768 * 768);
  const int tile = blockIdx.x;
  const int r0 = (tile / 12) * 64, c0 = (tile - (tile / 12) * 12) * 64;
  const int i = threadIdx.x >> 6, j = threadIdx.x & 63;
  #pragma unroll
  for (int it = 0; it < 16; ++it) {
    const int row = it * 4 + i;
    t[row][j] = src[(size_t)(r0 + row) * 768 + c0 + j];
  }
  __syncthreads();
  #pragma unroll
  for (int it = 0; it < 16; ++it) {
    const int row = it * 4 + i;
    dst[(size_t)(c0 + row) * 768 + r0 + j] = f2h(t[j][row]);
  }
  if (blockIdx.x == 0 && m == 0) {
    for (int k = threadIdx.x; k < 768; k += 256) {
      bcat[k] = bq[k];
      bcat[k + 768] = bk[k];
      bcat[k + 1536] = bv[k];
    }
  }
}

// ---------------- 256x256 GEMM, BK=64, 8 waves, 2-phase dbuf, XCD-swizzled --
// MODE 0: QKV. c in [0,2304): seg 0 -> Q [B,H,N,D], 1 -> K, 2 -> Vt [B,H,D,N]
//         grid = 9*32 = 288 (1-D). v = acc*scale + bias[c], f16 out.
// MODE 1: final. c in [0,768), fp32 out [M,768]. grid = 3*32 = 96 (1-D).
// XCD swizzle: g = bid&7 -> tm = g*4 + (li&3), tn = li>>2. Blocks sharing
// A-panels/B-panels co-reside on one XCD's L2.
template <int MODE>
__global__ __launch_bounds__(512, 2) void gemm256(
    const u16* __restrict__ A, const u16* __restrict__ Bt,
    const float* __restrict__ bias, const float* __restrict__ scale_p,
    u16* __restrict__ Oq, u16* __restrict__ Ok, u16* __restrict__ Ovt,
    float* __restrict__ Of) {
  __shared__ u16 As[2][256 * 64];   // 64 KB
  __shared__ u16 Bs[2][256 * 64];   // 64 KB
  const int K = 768, NK = 12;
  const int tid = threadIdx.x;
  const int w = tid >> 6, l = tid & 63;
  const int l15 = l & 15, lk = l >> 4;
  const int wr = w >> 2, wc = w & 3;          // wave grid 2M x 4N
  const int xr = l15 & 7;                     // read-side XOR key
  const int bid = blockIdx.x;
  const int g = bid & 7, li = bid >> 3;
  const int tn = li >> 2, tm = g * 4 + (li & 3);
  f32x4 acc[8][4] = {};
  const int rA = tid >> 3;                    // staging row 0..63 (+64*i)
  const int schunk = ((tid & 7) ^ (rA & 7)) * 8;  // pre-swizzled source chunk
  const u16* gA = A + (size_t)(tm * 256 + rA) * K + schunk;
  const u16* gB = Bt + (size_t)(tn * 256 + rA) * K + schunk;

  #define STAGE(buf, kt)                                              \
    {                                                                 \
      const int k0 = (kt) * 64;                                       \
      char* lA = (char*)As[buf] + w * 1024;                           \
      char* lB = (char*)Bs[buf] + w * 1024;                           \
      _Pragma("unroll")                                               \
      for (int i = 0; i < 4; ++i) {                                   \
        gload16(gA + k0 + (size_t)(i * 64) * K, lA + i * 8192);       \
        gload16(gB + k0 + (size_t)(i * 64) * K, lB + i * 8192);       \
      }                                                               \
    }

  STAGE(0, 0)
  __syncthreads();
  for (int kt = 0; kt < NK; ++kt) {
    const int buf = kt & 1;
    if (kt + 1 < NK) STAGE(buf ^ 1, kt + 1)
    #pragma unroll
    for (int kh = 0; kh < 2; ++kh) {
      short8 af[8], bf[4];
      #pragma unroll
      for (int mi = 0; mi < 8; ++mi) {
        const int row = wr * 128 + mi * 16 + l15;
        af[mi] = *(const short8*)&As[buf][row * 64 + (((kh * 4 + lk) ^ xr) * 8)];
      }
      #pragma unroll
      for (int ni = 0; ni < 4; ++ni) {
        const int row = wc * 64 + ni * 16 + l15;
        bf[ni] = *(const short8*)&Bs[buf][row * 64 + (((kh * 4 + lk) ^ xr) * 8)];
      }
      #pragma unroll
      for (int mi = 0; mi < 8; ++mi)
        #pragma unroll
        for (int ni = 0; ni < 4; ++ni)
          acc[mi][ni] = mfma16(af[mi], bf[ni], acc[mi][ni]);
    }
    __syncthreads();   // drains vmcnt (stage) + lgkm; one barrier per K-tile
  }
  #undef STAGE

  float s = 1.0f;
  if (MODE == 0) s = *scale_p;
  const int seg = (MODE == 0) ? (tn / 3) : 0;
  #pragma unroll
  for (int mi = 0; mi < 8; ++mi) {
    #pragma unroll
    for (int ni = 0; ni < 4; ++ni) {
      #pragma unroll
      for (int j = 0; j < 4; ++j) {
        const int gm = tm * 256 + wr * 128 + mi * 16 + lk * 4 + j;
        const int c = tn * 256 + wc * 64 + ni * 16 + l15;
        if (MODE == 0) {
          const int gc = c - seg * 768;
          const float v = acc[mi][ni][j] * s + bias[c];
          const int b = gm >> 10, n = gm & 1023, h = gc >> 6, d = gc & 63;
          if (seg == 0)
            Oq[(((size_t)b * 12 + h) * 1024 + n) * 64 + d] = f2h(v);
          else if (seg == 1)
            Ok[(((size_t)b * 12 + h) * 1024 + n) * 64 + d] = f2h(v);
          else
            Ovt[(((size_t)b * 12 + h) * 64 + d) * 1024 + n] = f2h(v);
        } else {
          Of[(size_t)gm * 768 + c] = acc[mi][ni][j] + bias[c];
        }
      }
    }
  }
}

// ---------------- fused attention (flash, 2-pass exact-max) -----------------
__global__ __launch_bounds__(512, 4) void attn_kernel(
    const u16* __restrict__ Q, const u16* __restrict__ K,
    const u16* __restrict__ Vt, u16* __restrict__ ctx) {
  __shared__ u16 Ks[2][64 * 64];   // 16 KB
  __shared__ u16 Vs[2][64 * 64];   // 16 KB
  __shared__ u16 Pw[8][16 * 40];   // 10 KB, wave-private P transpose buffers
  const int bh = blockIdx.x, qt = blockIdx.y;
  const int b = bh / 12, h = bh - b * 12;
  const int tid = threadIdx.x;
  const int w = tid >> 6, l = tid & 63;
  const int l15 = l & 15, lk = l >> 4;
  const int xr = l15 & 7;

  const size_t qoff = ((size_t)bh * 1024 + qt * 128 + w * 16 + l15) * 64 + lk * 8;
  const short8 qa0 = *(const short8*)(Q + qoff);
  const short8 qa1 = *(const short8*)(Q + qoff + 32);

  const int srow = w * 8 + (l >> 3);
  const int schunk = ((l & 7) ^ ((l >> 3) & 7)) * 8;
  const u16* Kg = K + ((size_t)bh * 1024 + srow) * 64 + schunk;
  const u16* Vg = Vt + ((size_t)bh * 64 + srow) * 1024 + schunk;
  u16* const ksd[2] = {&Ks[0][w * 512], &Ks[1][w * 512]};
  u16* const vsd[2] = {&Vs[0][w * 512], &Vs[1][w * 512]};

  // ---- pass A: exact row max ----
  f32x4 mx = {-3e38f, -3e38f, -3e38f, -3e38f};
  gload16(Kg, ksd[0]);
  __syncthreads();
  for (int kt = 0; kt < 16; ++kt) {
    const int buf = kt & 1;
    if (kt < 15) gload16(Kg + (size_t)(kt + 1) * 4096, ksd[buf ^ 1]);
    const u16* kb = Ks[buf];
    #pragma unroll
    for (int ks = 0; ks < 4; ++ks) {
      short8 k0 = *(const short8*)&kb[(ks * 16 + l15) * 64 + ((lk ^ xr) * 8)];
      short8 k1 = *(const short8*)&kb[(ks * 16 + l15) * 64 + (((lk + 4) ^ xr) * 8)];
      f32x4 sv = {0.f, 0.f, 0.f, 0.f};
      sv = mfma16(qa0, k0, sv);
      sv = mfma16(qa1, k1, sv);
      #pragma unroll
      for (int j = 0; j < 4; ++j) mx[j] = fmaxf(mx[j], sv[j]);
    }
    __syncthreads();
  }
  #pragma unroll
  for (int o = 1; o < 16; o <<= 1) {
    #pragma unroll
    for (int j = 0; j < 4; ++j) mx[j] = fmaxf(mx[j], __shfl_xor(mx[j], o));
  }
  f32x4 mz;
  #pragma unroll
  for (int j = 0; j < 4; ++j) mz[j] = mx[j] * LOG2E_F;

  // ---- pass B: recompute S, ITA softmax, PV ----
  f32x4 sum = {0.f, 0.f, 0.f, 0.f};
  f32x4 pv[4] = {};
  u16* const pw = Pw[w];
  gload16(Kg, ksd[0]);
  gload16(Vg, vsd[0]);
  __syncthreads();
  for (int kt = 0; kt < 16; ++kt) {
    const int buf = kt & 1;
    if (kt < 15) {
      gload16(Kg + (size_t)(kt + 1) * 4096, ksd[buf ^ 1]);
      gload16(Vg + (size_t)(kt + 1) * 64, vsd[buf ^ 1]);
    }
    const u16* kb = Ks[buf];
    const u16* vb = Vs[buf];
    #pragma unroll
    for (int ko = 0; ko < 2; ++ko) {
      #pragma unroll
      for (int ks2 = 0; ks2 < 2; ++ks2) {
        const int ks = ko * 2 + ks2;
        short8 k0 = *(const short8*)&kb[(ks * 16 + l15) * 64 + ((lk ^ xr) * 8)];
        short8 k1 = *(const short8*)&kb[(ks * 16 + l15) * 64 + (((lk + 4) ^ xr) * 8)];
        f32x4 sv = {0.f, 0.f, 0.f, 0.f};
        sv = mfma16(qa0, k0, sv);
        sv = mfma16(qa1, k1, sv);
        #pragma unroll
        for (int j = 0; j < 4; ++j) {
          float z = sv[j] * LOG2E_F;
          float zz = z - mz[j];
          float zi = floorf(zz);
          float p = ldexpf(1.0f + (zz - zi), (int)zi);
          sum[j] += p;
          pw[(lk * 4 + j) * 40 + ks2 * 16 + l15] = f2h(p);
        }
      }
      asm volatile("s_waitcnt lgkmcnt(0)" ::: "memory");
      short8 pa = *(const short8*)&pw[l15 * 40 + lk * 8];
      #pragma unroll
      for (int dt = 0; dt < 4; ++dt) {
        short8 vv = *(const short8*)&vb[(dt * 16 + l15) * 64 +
                                        (((lk + 4 * ko) ^ xr) * 8)];
        pv[dt] = mfma16(pa, vv, pv[dt]);
      }
    }
    __syncthreads();
  }
  #pragma unroll
  for (int o = 1; o < 16; o <<= 1) {
    #pragma unroll
    for (int j = 0; j < 4; ++j) sum[j] += __shfl_xor(sum[j], o);
  }
  const int nrow = qt * 128 + w * 16 + lk * 4;
  #pragma unroll
  for (int dt = 0; dt < 4; ++dt) {
    #pragma unroll
    for (int j = 0; j < 4; ++j) {
      float v = pv[dt][j] / sum[j];
      ctx[((size_t)b * 1024 + nrow + j) * 768 + h * 64 + dt * 16 + l15] = f2h(v);
    }
  }
}

// ---------------- host ----------------
extern "C" void kernel_launch(void* const* d_in, const int* in_sizes, int n_in,
                              void* d_out, int out_size, void* d_ws, size_t ws_size,
                              hipStream_t stream) {
  const float* x  = (const float*)d_in[0];
  const float* Wq = (const float*)d_in[1];
  const float* bq = (const float*)d_in[2];
  const float* Wk = (const float*)d_in[3];
  const float* bk = (const float*)d_in[4];
  const float* Wv = (const float*)d_in[5];
  const float* bv = (const float*)d_in[6];
  const float* Wo = (const float*)d_in[7];
  const float* bo = (const float*)d_in[8];
  float* out = (float*)d_out;

  char* ws = (char*)d_ws;
  float* part  = (float*)ws;               // 1024 f32
  double* dsc  = (double*)(ws + 4096);     // {s, 1/s} f64
  float* dscf  = (float*)(ws + 4112);      // s f32
  float* bcat  = (float*)(ws + 8192);      // 2304 f32
  size_t off = 8192 + 16384;
  const size_t WB = (size_t)768 * 768;
  const size_t XB = (size_t)8192 * 768;
  u16* xq   = (u16*)(ws + off); off += XB * 2;
  u16* Wcat = (u16*)(ws + off); off += 3 * WB * 2;
  u16* Wot  = (u16*)(ws + off); off += WB * 2;
  u16* Qb   = (u16*)(ws + off); off += XB * 2;
  u16* Kb   = (u16*)(ws + off); off += XB * 2;
  u16* Vtb  = (u16*)(ws + off); off += XB * 2;
  u16* ctx  = xq;  // xq dead after gemm256<0>; attn runs after -> safe alias
  (void)ws_size; (void)in_sizes; (void)n_in; (void)out_size;

  const int n4 = (8 * 1024 * 768) / 4;
  amax_part_kernel<<<1024, 256, 0, stream>>>((const float4*)x, part, n4);
  amax_fin_kernel<<<1, 256, 0, stream>>>(part, dsc, dscf);
  quant_kernel<<<2048, 256, 0, stream>>>((const float4*)x, xq, dsc, n4);
  prep_weights_kernel<<<dim3(144, 4), 256, 0, stream>>>(
      Wq, Wk, Wv, Wo, bq, bk, bv, Wcat, Wot, bcat);
  gemm256<0><<<288, 512, 0, stream>>>(xq, Wcat, bcat, dscf, Qb, Kb, Vtb, nullptr);
  attn_kernel<<<dim3(96, 8), 512, 0, stream>>>(Qb, Kb, Vtb, ctx);
  gemm256<1><<<96, 512, 0, stream>>>(ctx, Wot, bo, nullptr,
                                     nullptr, nullptr, nullptr, out);
}

// Round 7
// 150.703 us; speedup vs baseline: 1.3615x; 1.3492x over previous
//
#include <hip/hip_runtime.h>

// ITA Self-Attention QAT — round 7 (128^2 GEMM + coalesced epilogues + XCD)
// B=8, N=1024, E=768, P=768, H=12, D=64
//
// vs round 6 (203us, gemm256 QKV 126us): 256^2 structure collapsed staging
// throughput (1.75 vs 4.6 TB/s at 128^2) and its Vt/QK epilogues store 2B
// scattered elements (64 cache lines per store instr for Vt). Fix:
//  - back to round-4 128^2 BK=32 K-loop (linear gload16 staging, dbuf)
//  - epilogue: wave tile -> 9KB LDS scratch (reuses staging bufs) -> 128B
//    contiguous short8 stores (Vt transposed in LDS)
//  - XCD-swizzled 1-D grid (FETCH -62% proven round 6), 4 blocks/CU
// attn + prolog unchanged from round 6.

typedef unsigned short u16;
typedef __attribute__((ext_vector_type(8))) short short8;
typedef __attribute__((ext_vector_type(8))) _Float16 half8;
typedef __attribute__((ext_vector_type(4))) float f32x4;

#define LOG2E_F 1.4426950408889634f

static __device__ __forceinline__ half8 s2h(short8 s) {
  union { short8 s; half8 h; } u; u.s = s; return u.h;
}
static __device__ __forceinline__ f32x4 mfma16(short8 a, short8 b, f32x4 c) {
  return __builtin_amdgcn_mfma_f32_16x16x32_f16(s2h(a), s2h(b), c, 0, 0, 0);
}
static __device__ __forceinline__ u16 f2h(float f) {
  union { _Float16 h; u16 u; } v; v.h = (_Float16)f; return v.u;
}
static __device__ __forceinline__ void gload16(const void* g, void* l) {
  __builtin_amdgcn_global_load_lds(
      (const __attribute__((address_space(1))) void*)g,
      (__attribute__((address_space(3))) void*)l, 16, 0, 0);
}

// ---------------- amax reduction ----------------
__global__ __launch_bounds__(256) void amax_part_kernel(
    const float4* __restrict__ x, float* __restrict__ part, int n4) {
  float m = 0.f;
  int i = blockIdx.x * 256 + threadIdx.x;
  const int stride = gridDim.x * 256;
  for (; i < n4; i += stride) {
    float4 v = x[i];
    m = fmaxf(m, fmaxf(fmaxf(fabsf(v.x), fabsf(v.y)),
                       fmaxf(fabsf(v.z), fabsf(v.w))));
  }
  #pragma unroll
  for (int o = 1; o < 64; o <<= 1) m = fmaxf(m, __shfl_xor(m, o));
  __shared__ float sw[4];
  if ((threadIdx.x & 63) == 0) sw[threadIdx.x >> 6] = m;
  __syncthreads();
  if (threadIdx.x == 0)
    part[blockIdx.x] = fmaxf(fmaxf(sw[0], sw[1]), fmaxf(sw[2], sw[3]));
}

__global__ __launch_bounds__(256) void amax_fin_kernel(
    const float* __restrict__ part, double* __restrict__ dsc,
    float* __restrict__ dscf) {
  const int t = threadIdx.x;
  float m = fmaxf(fmaxf(part[t], part[t + 256]),
                  fmaxf(part[t + 512], part[t + 768]));
  #pragma unroll
  for (int o = 1; o < 64; o <<= 1) m = fmaxf(m, __shfl_xor(m, o));
  __shared__ float sw[4];
  if ((t & 63) == 0) sw[t >> 6] = m;
  __syncthreads();
  if (t == 0) {
    double sd = (double)(fmaxf(fmaxf(sw[0], sw[1]), fmaxf(sw[2], sw[3]))) / 127.0;
    if (sd < 1e-8) sd = 1e-8;
    dsc[0] = sd;
    dsc[1] = 1.0 / sd;
    dscf[0] = (float)sd;
  }
}

// ---------------- quantize: xq = clip(rint(x/s),-128,127), exact in f16 -----
__global__ __launch_bounds__(256) void quant_kernel(
    const float4* __restrict__ x, u16* __restrict__ xq,
    const double* __restrict__ dsc, int n4) {
  const double rinv = dsc[1];
  int i = blockIdx.x * 256 + threadIdx.x;
  const int stride = gridDim.x * 256;
  for (; i < n4; i += stride) {
    float4 v = x[i];
    ushort4 u;
    u.x = f2h((float)fmin(fmax(rint((double)v.x * rinv), -128.0), 127.0));
    u.y = f2h((float)fmin(fmax(rint((double)v.y * rinv), -128.0), 127.0));
    u.z = f2h((float)fmin(fmax(rint((double)v.z * rinv), -128.0), 127.0));
    u.w = f2h((float)fmin(fmax(rint((double)v.w * rinv), -128.0), 127.0));
    *(ushort4*)&xq[(size_t)i * 4] = u;
  }
}

// ------- weight prep: LDS-tiled transpose fp32->f16 (coalesced both sides) --
__global__ __launch_bounds__(256) void prep_weights_kernel(
    const float* __restrict__ Wq, const float* __restrict__ Wk,
    const float* __restrict__ Wv, const float* __restrict__ Wo,
    const float* __restrict__ bq, const float* __restrict__ bk,
    const float* __restrict__ bv,
    u16* __restrict__ Wcat, u16* __restrict__ Wot, float* __restrict__ bcat) {
  __shared__ float t[64][65];
  const int m = blockIdx.y;
  const float* src = (m == 0) ? Wq : (m == 1) ? Wk : (m == 2) ? Wv : Wo;
  u16* dst = (m == 3) ? Wot : (Wcat + (size_t)m * 768 * 768);
  const int tile = blockIdx.x;
  const int r0 = (tile / 12) * 64, c0 = (tile - (tile / 12) * 12) * 64;
  const int i = threadIdx.x >> 6, j = threadIdx.x & 63;
  #pragma unroll
  for (int it = 0; it < 16; ++it) {
    const int row = it * 4 + i;
    t[row][j] = src[(size_t)(r0 + row) * 768 + c0 + j];
  }
  __syncthreads();
  #pragma unroll
  for (int it = 0; it < 16; ++it) {
    const int row = it * 4 + i;
    dst[(size_t)(c0 + row) * 768 + r0 + j] = f2h(t[j][row]);
  }
  if (blockIdx.x == 0 && m == 0) {
    for (int k = threadIdx.x; k < 768; k += 256) {
      bcat[k] = bq[k];
      bcat[k + 768] = bk[k];
      bcat[k + 1536] = bv[k];
    }
  }
}

// ---------------- 128x128 GEMM, BK=32, 4 waves, 2-phase dbuf, XCD grid ------
// MODE 0: QKV, NT=18 col-tiles. seg 0 -> Q [B,H,N,D], 1 -> K, 2 -> Vt [B,H,D,N]
//         f16 out via LDS-staged coalesced short8 stores. grid = 1152 (1-D).
// MODE 1: final, NT=6, fp32 out [M,768] direct (already coalesced). grid 384.
// XCD swizzle: g=bid&7, li=bid>>3: tn=li>>3, tm=g*8+(li&7). Each XCD works one
// batch's A rows (1.5MB) + a rotating B panel -> L2-resident staging.
template <int MODE>
__global__ __launch_bounds__(256, 4) void gemm128(
    const u16* __restrict__ A, const u16* __restrict__ Bt,
    const float* __restrict__ bias, const float* __restrict__ scale_p,
    u16* __restrict__ Oq, u16* __restrict__ Ok, u16* __restrict__ Ovt,
    float* __restrict__ Of) {
  __shared__ u16 S[4][4608];   // S[0..1]=A dbuf (4096 used), S[2..3]=B dbuf;
                               // epilogue: S[w] = 64x72 u16 scratch per wave
  const int K = 768, nk = 24;
  const int tid = threadIdx.x;
  const int w = tid >> 6, l = tid & 63;
  const int l15 = l & 15, lk = l >> 4;
  const int wr = w >> 1, wc = w & 1;
  const int bid = blockIdx.x;
  const int g = bid & 7, li = bid >> 3;
  const int tn = li >> 3, tm = g * 8 + (li & 7);
  f32x4 acc[4][4] = {};
  const int rA = tid >> 2;
  const int c8 = (tid & 3) * 8;
  const u16* gA = A + (size_t)(tm * 128 + rA) * K + c8;
  const u16* gB = Bt + (size_t)(tn * 128 + rA) * K + c8;
  {
    char* lA = (char*)S[0] + w * 1024;
    char* lB = (char*)S[2] + w * 1024;
    gload16(gA, lA);
    gload16(gA + (size_t)64 * K, lA + 4096);
    gload16(gB, lB);
    gload16(gB + (size_t)64 * K, lB + 4096);
  }
  __syncthreads();
  for (int kt = 0; kt < nk; ++kt) {
    const int buf = kt & 1;
    if (kt + 1 < nk) {
      const int k0 = (kt + 1) * 32;
      char* lA = (char*)S[buf ^ 1] + w * 1024;
      char* lB = (char*)S[2 + (buf ^ 1)] + w * 1024;
      gload16(gA + k0, lA);
      gload16(gA + k0 + (size_t)64 * K, lA + 4096);
      gload16(gB + k0, lB);
      gload16(gB + k0 + (size_t)64 * K, lB + 4096);
    }
    short8 af[4], bf[4];
    #pragma unroll
    for (int mi = 0; mi < 4; ++mi)
      af[mi] = *(const short8*)&S[buf][(wr * 64 + mi * 16 + l15) * 32 + lk * 8];
    #pragma unroll
    for (int ni = 0; ni < 4; ++ni)
      bf[ni] = *(const short8*)&S[2 + buf][(wc * 64 + ni * 16 + l15) * 32 + lk * 8];
    #pragma unroll
    for (int mi = 0; mi < 4; ++mi)
      #pragma unroll
      for (int ni = 0; ni < 4; ++ni)
        acc[mi][ni] = mfma16(af[mi], bf[ni], acc[mi][ni]);
    __syncthreads();
  }

  if (MODE == 1) {
    #pragma unroll
    for (int mi = 0; mi < 4; ++mi)
      #pragma unroll
      for (int ni = 0; ni < 4; ++ni)
        #pragma unroll
        for (int j = 0; j < 4; ++j) {
          const int gm = tm * 128 + wr * 64 + mi * 16 + lk * 4 + j;
          const int c = tn * 128 + wc * 64 + ni * 16 + l15;
          Of[(size_t)gm * 768 + c] = acc[mi][ni][j] + bias[c];
        }
    return;
  }

  // MODE 0 epilogue: stage wave tile in LDS, store coalesced 128B rows.
  __syncthreads();               // all waves done reading staging bufs
  const float s = *scale_p;
  const int seg = tn / 6;        // 0:Q 1:K 2:Vt
  const int h = (tn - seg * 6) * 2 + wc;   // head index for this wave's 64 cols
  u16* esc = &S[w][0];           // 64 x 72 u16 (stride 72 -> 16B-aligned rows)
  #pragma unroll
  for (int mi = 0; mi < 4; ++mi) {
    #pragma unroll
    for (int ni = 0; ni < 4; ++ni) {
      #pragma unroll
      for (int j = 0; j < 4; ++j) {
        const float v = acc[mi][ni][j] * s + bias[tn * 128 + wc * 64 + ni * 16 + l15];
        const int row = mi * 16 + lk * 4 + j;   // n-offset within wave tile
        const int col = ni * 16 + l15;          // d-offset within wave tile
        if (seg < 2) esc[row * 72 + col] = f2h(v);
        else         esc[col * 72 + row] = f2h(v);   // transposed: [d][n]
      }
    }
  }
  asm volatile("s_waitcnt lgkmcnt(0)" ::: "memory");
  const int n0 = tm * 128 + wr * 64;   // 64 consecutive n, same batch
  const int b = n0 >> 10, nn = n0 & 1023;
  u16* outp = (seg == 0) ? Oq : (seg == 1) ? Ok : Ovt;
  #pragma unroll
  for (int it = 0; it < 8; ++it) {
    const int r = it * 8 + (l >> 3);
    const int cc = (l & 7) * 8;
    short8 vv = *(const short8*)&esc[r * 72 + cc];
    size_t o;
    if (seg < 2)   // row r = n-offset; 128B contiguous d-run
      o = (((size_t)b * 12 + h) * 1024 + nn + r) * 64 + cc;
    else           // row r = d; 128B contiguous n-run
      o = (((size_t)b * 12 + h) * 64 + r) * 1024 + nn + cc;
    *(short8*)&outp[o] = vv;
  }
}

// ---------------- fused attention (flash, 2-pass exact-max) -----------------
__global__ __launch_bounds__(512, 4) void attn_kernel(
    const u16* __restrict__ Q, const u16* __restrict__ K,
    const u16* __restrict__ Vt, u16* __restrict__ ctx) {
  __shared__ u16 Ks[2][64 * 64];   // 16 KB
  __shared__ u16 Vs[2][64 * 64];   // 16 KB
  __shared__ u16 Pw[8][16 * 40];   // 10 KB, wave-private P transpose buffers
  const int bh = blockIdx.x, qt = blockIdx.y;
  const int b = bh / 12, h = bh - b * 12;
  const int tid = threadIdx.x;
  const int w = tid >> 6, l = tid & 63;
  const int l15 = l & 15, lk = l >> 4;
  const int xr = l15 & 7;

  const size_t qoff = ((size_t)bh * 1024 + qt * 128 + w * 16 + l15) * 64 + lk * 8;
  const short8 qa0 = *(const short8*)(Q + qoff);
  const short8 qa1 = *(const short8*)(Q + qoff + 32);

  const int srow = w * 8 + (l >> 3);
  const int schunk = ((l & 7) ^ ((l >> 3) & 7)) * 8;
  const u16* Kg = K + ((size_t)bh * 1024 + srow) * 64 + schunk;
  const u16* Vg = Vt + ((size_t)bh * 64 + srow) * 1024 + schunk;
  u16* const ksd[2] = {&Ks[0][w * 512], &Ks[1][w * 512]};
  u16* const vsd[2] = {&Vs[0][w * 512], &Vs[1][w * 512]};

  // ---- pass A: exact row max ----
  f32x4 mx = {-3e38f, -3e38f, -3e38f, -3e38f};
  gload16(Kg, ksd[0]);
  __syncthreads();
  for (int kt = 0; kt < 16; ++kt) {
    const int buf = kt & 1;
    if (kt < 15) gload16(Kg + (size_t)(kt + 1) * 4096, ksd[buf ^ 1]);
    const u16* kb = Ks[buf];
    #pragma unroll
    for (int ks = 0; ks < 4; ++ks) {
      short8 k0 = *(const short8*)&kb[(ks * 16 + l15) * 64 + ((lk ^ xr) * 8)];
      short8 k1 = *(const short8*)&kb[(ks * 16 + l15) * 64 + (((lk + 4) ^ xr) * 8)];
      f32x4 sv = {0.f, 0.f, 0.f, 0.f};
      sv = mfma16(qa0, k0, sv);
      sv = mfma16(qa1, k1, sv);
      #pragma unroll
      for (int j = 0; j < 4; ++j) mx[j] = fmaxf(mx[j], sv[j]);
    }
    __syncthreads();
  }
  #pragma unroll
  for (int o = 1; o < 16; o <<= 1) {
    #pragma unroll
    for (int j = 0; j < 4; ++j) mx[j] = fmaxf(mx[j], __shfl_xor(mx[j], o));
  }
  f32x4 mz;
  #pragma unroll
  for (int j = 0; j < 4; ++j) mz[j] = mx[j] * LOG2E_F;

  // ---- pass B: recompute S, ITA softmax, PV ----
  f32x4 sum = {0.f, 0.f, 0.f, 0.f};
  f32x4 pv[4] = {};
  u16* const pw = Pw[w];
  gload16(Kg, ksd[0]);
  gload16(Vg, vsd[0]);
  __syncthreads();
  for (int kt = 0; kt < 16; ++kt) {
    const int buf = kt & 1;
    if (kt < 15) {
      gload16(Kg + (size_t)(kt + 1) * 4096, ksd[buf ^ 1]);
      gload16(Vg + (size_t)(kt + 1) * 64, vsd[buf ^ 1]);
    }
    const u16* kb = Ks[buf];
    const u16* vb = Vs[buf];
    #pragma unroll
    for (int ko = 0; ko < 2; ++ko) {
      #pragma unroll
      for (int ks2 = 0; ks2 < 2; ++ks2) {
        const int ks = ko * 2 + ks2;
        short8 k0 = *(const short8*)&kb[(ks * 16 + l15) * 64 + ((lk ^ xr) * 8)];
        short8 k1 = *(const short8*)&kb[(ks * 16 + l15) * 64 + (((lk + 4) ^ xr) * 8)];
        f32x4 sv = {0.f, 0.f, 0.f, 0.f};
        sv = mfma16(qa0, k0, sv);
        sv = mfma16(qa1, k1, sv);
        #pragma unroll
        for (int j = 0; j < 4; ++j) {
          float z = sv[j] * LOG2E_F;
          float zz = z - mz[j];
          float zi = floorf(zz);
          float p = ldexpf(1.0f + (zz - zi), (int)zi);
          sum[j] += p;
          pw[(lk * 4 + j) * 40 + ks2 * 16 + l15] = f2h(p);
        }
      }
      asm volatile("s_waitcnt lgkmcnt(0)" ::: "memory");
      short8 pa = *(const short8*)&pw[l15 * 40 + lk * 8];
      #pragma unroll
      for (int dt = 0; dt < 4; ++dt) {
        short8 vv = *(const short8*)&vb[(dt * 16 + l15) * 64 +
                                        (((lk + 4 * ko) ^ xr) * 8)];
        pv[dt] = mfma16(pa, vv, pv[dt]);
      }
    }
    __syncthreads();
  }
  #pragma unroll
  for (int o = 1; o < 16; o <<= 1) {
    #pragma unroll
    for (int j = 0; j < 4; ++j) sum[j] += __shfl_xor(sum[j], o);
  }
  const int nrow = qt * 128 + w * 16 + lk * 4;
  #pragma unroll
  for (int dt = 0; dt < 4; ++dt) {
    #pragma unroll
    for (int j = 0; j < 4; ++j) {
      float v = pv[dt][j] / sum[j];
      ctx[((size_t)b * 1024 + nrow + j) * 768 + h * 64 + dt * 16 + l15] = f2h(v);
    }
  }
}

// ---------------- host ----------------
extern "C" void kernel_launch(void* const* d_in, const int* in_sizes, int n_in,
                              void* d_out, int out_size, void* d_ws, size_t ws_size,
                              hipStream_t stream) {
  const float* x  = (const float*)d_in[0];
  const float* Wq = (const float*)d_in[1];
  const float* bq = (const float*)d_in[2];
  const float* Wk = (const float*)d_in[3];
  const float* bk = (const float*)d_in[4];
  const float* Wv = (const float*)d_in[5];
  const float* bv = (const float*)d_in[6];
  const float* Wo = (const float*)d_in[7];
  const float* bo = (const float*)d_in[8];
  float* out = (float*)d_out;

  char* ws = (char*)d_ws;
  float* part  = (float*)ws;               // 1024 f32
  double* dsc  = (double*)(ws + 4096);     // {s, 1/s} f64
  float* dscf  = (float*)(ws + 4112);      // s f32
  float* bcat  = (float*)(ws + 8192);      // 2304 f32
  size_t off = 8192 + 16384;
  const size_t WB = (size_t)768 * 768;
  const size_t XB = (size_t)8192 * 768;
  u16* xq   = (u16*)(ws + off); off += XB * 2;
  u16* Wcat = (u16*)(ws + off); off += 3 * WB * 2;
  u16* Wot  = (u16*)(ws + off); off += WB * 2;
  u16* Qb   = (u16*)(ws + off); off += XB * 2;
  u16* Kb   = (u16*)(ws + off); off += XB * 2;
  u16* Vtb  = (u16*)(ws + off); off += XB * 2;
  u16* ctx  = xq;  // xq dead after gemm128<0>; attn runs after -> safe alias
  (void)ws_size; (void)in_sizes; (void)n_in; (void)out_size;

  const int n4 = (8 * 1024 * 768) / 4;
  amax_part_kernel<<<1024, 256, 0, stream>>>((const float4*)x, part, n4);
  amax_fin_kernel<<<1, 256, 0, stream>>>(part, dsc, dscf);
  quant_kernel<<<2048, 256, 0, stream>>>((const float4*)x, xq, dsc, n4);
  prep_weights_kernel<<<dim3(144, 4), 256, 0, stream>>>(
      Wq, Wk, Wv, Wo, bq, bk, bv, Wcat, Wot, bcat);
  gemm128<0><<<1152, 256, 0, stream>>>(xq, Wcat, bcat, dscf,
                                       Qb, Kb, Vtb, nullptr);
  attn_kernel<<<dim3(96, 8), 512, 0, stream>>>(Qb, Kb, Vtb, ctx);
  gemm128<1><<<384, 256, 0, stream>>>(ctx, Wot, bo, nullptr,
                                      nullptr, nullptr, nullptr, out);
}